// Round 1
// baseline (367.173 us; speedup 1.0000x reference)
//
#include <hip/hip_runtime.h>
#include <hip/hip_bf16.h>
#include <math.h>

#define N_ENT   40000
#define RANK    200
#define NB      500
#define K_REAL  1000   // RANK*5
#define K_PAD   1024
#define M_PAD   512

typedef __attribute__((ext_vector_type(8))) short       short8;    // 8 bf16 MFMA A/B frag
typedef __attribute__((ext_vector_type(4))) float       f32x4;     // MFMA C/D frag

__device__ __forceinline__ unsigned short f2bf(float f) {
    union { float f; unsigned int u; } v; v.f = f;
    unsigned int u = v.u;
    return (unsigned short)((u + 0x7FFFu + ((u >> 16) & 1u)) >> 16);  // RNE
}

// truncating bf16x2 pack: low half from x, high half from y
__device__ __forceinline__ unsigned int pack_hi(float x, float y) {
    return (__float_as_uint(x) >> 16) | (__float_as_uint(y) & 0xFFFF0000u);
}

// async global->LDS 16B: HW writes wave-uniform LDS base + lane*16
__device__ __forceinline__ void gld_lds16(const void* g, void* l) {
    __builtin_amdgcn_global_load_lds(
        (const __attribute__((address_space(1))) unsigned int*)g,
        (__attribute__((address_space(3))) unsigned int*)l,
        16, 0, 0);
}

// ---------------------------------------------------------------------------
// gather + gelu/rotate/boost/negate -> x bf16 [512][1024] padded; reg_rel f32
// (unchanged from verified kernel)
// ---------------------------------------------------------------------------
__global__ __launch_bounds__(256) void lkg_prep(
    const int* __restrict__ queries,
    const float* __restrict__ ent,
    const float* __restrict__ rot,
    const float* __restrict__ boo,
    unsigned short* __restrict__ xws,
    float* __restrict__ out)
{
    const int b   = blockIdx.x;
    const int tid = threadIdx.x;
    unsigned short* xrow = xws + (size_t)b * K_PAD;

    if (b >= NB) {                       // zero pad rows 500..511
        ((uint2*)xrow)[tid] = make_uint2(0u, 0u);
        return;
    }
    if (tid >= RANK) {                   // zero K-pad cols 1000..1023
        int c = tid - RANK;
        if (c < K_PAD - K_REAL) xrow[K_REAL + c] = 0;
        return;
    }

    const int d  = tid;
    const int q0 = queries[b * 3 + 0];
    const int q1 = queries[b * 3 + 1];

    const float* L  = ent + (size_t)q0 * (RANK * 5) + d * 5;
    const float* R  = rot + (size_t)q1 * (RANK * 4) + d * 4;
    const float* Bo = boo + (size_t)q1 * (RANK * 4) + d * 4;

    const float t = L[0], r = L[1], i = L[2], j = L[3], k = L[4];
    const float r0 = R[0],  r1 = R[1],  r2 = R[2],  r3 = R[3];
    const float o0 = Bo[0], o1 = Bo[1], o2 = Bo[2], o3 = Bo[3];

    out[(size_t)NB * N_ENT + (size_t)b * RANK + d] =
        sqrtf(r0*r0 + r1*r1 + r2*r2 + r3*r3) +
        sqrtf(o0*o0 + o1*o1 + o2*o2 + o3*o3);

    const float is2 = 0.70710678118654752440f;
    const float rr = 0.5f * r0 * (1.0f + erff(r0 * is2));
    const float ri = 0.5f * r1 * (1.0f + erff(r1 * is2));
    const float rj = 0.5f * r2 * (1.0f + erff(r2 * is2));
    const float rk = 0.5f * r3 * (1.0f + erff(r3 * is2));

    const float s0 = r*rr - i*ri - j*rj - k*rk;
    const float s1 = r*ri + rr*i + j*rk - rj*k;
    const float s2 = r*rj + rr*j + k*ri - rk*i;
    const float s3 = r*rk + rr*k + i*rj - ri*j;

    const float b0 = 0.25f / (1.0f + expf(-o0));
    const float b1 = 0.25f / (1.0f + expf(-o1));
    const float b2 = 0.25f / (1.0f + expf(-o2));
    const float b3 = 0.25f / (1.0f + expf(-o3));

    const float bsq = b0*b0 + b1*b1 + b2*b2 + b3*b3;
    const float xt  = t * bsq + b0*s0 + b1*s1 + b2*s2 + b3*s3;

    const float m00 = sqrtf(1.0f + b0*b0), m11 = sqrtf(1.0f + b1*b1);
    const float m22 = sqrtf(1.0f + b2*b2), m33 = sqrtf(1.0f + b3*b3);
    const float m01 = sqrtf(b0*b1), m02 = sqrtf(b0*b2), m03 = sqrtf(b0*b3);
    const float m12 = sqrtf(b1*b2), m13 = sqrtf(b1*b3), m23 = sqrtf(b2*b3);

    const float xs0 = t*b0 + m00*s0 + m01*s1 + m02*s2 + m03*s3;
    const float xs1 = t*b1 + m01*s0 + m11*s1 + m12*s2 + m13*s3;
    const float xs2 = t*b2 + m02*s0 + m12*s1 + m22*s2 + m23*s3;
    const float xs3 = t*b3 + m03*s0 + m13*s1 + m23*s2 + m33*s3;

    unsigned short* w = xrow + d * 5;
    w[0] = f2bf(-xt);
    w[1] = f2bf(xs0);
    w[2] = f2bf(xs1);
    w[3] = f2bf(xs2);
    w[4] = f2bf(xs3);
}

// ---------------------------------------------------------------------------
// GEMM v5: full-M blocks. Tile = 512m x 64n, 512 threads = 8 waves, each wave
// the same verified 64x64 sub-tile (4x4 f32x4 acc) as v4 (wy->wave, wx->0).
// Grid = 625 n-tiles = 40000/64 exactly -> EVERY ent row staged exactly once
// (FETCH ~333MB -> ~175MB; xbf A = 1MB, re-read from L2 by all blocks).
// 2-phase pipeline (learn_hip T3 minimum recipe): double-buffered LDS,
// STAGE(next) issued BEFORE compute(cur), ONE __syncthreads per tile, so the
// vmcnt(0) drain at the barrier waits on loads that had the whole compute
// phase to land.
// Swizzles identical to v4 (applied on GLOBAL addr, LDS stays lane-linear as
// global_load_lds requires):
//   A: chunk cc stores k-chunk cc ^ ((row>>1)&3)   -> <=2-way frag reads
//   B: chunk cc stores k-chunk cc ^ (row&7)        -> <=2-way frag reads
// B tail kt=31: slots with k>=1000 clamp the source addr to k=996 -> finite
// garbage multiplied by A's zero-pad columns (xbf cols 1000..1023 are 0).
// LDS: 2 x (A 32KB + B 8KB) = 80KB -> 2 blocks/CU; launch_bounds(512,4)
// caps VGPR at 128 so occupancy stays LDS-limited, not VGPR-limited.
// ---------------------------------------------------------------------------
__global__ __launch_bounds__(512, 4) void lkg_gemm5(
    const unsigned short* __restrict__ xbf,
    const float* __restrict__ ent,
    float* __restrict__ out)
{
    __shared__ __align__(16) unsigned char smx[2 * 40960];   // 80 KB

    const int n0   = blockIdx.x * 64;
    const int tid  = threadIdx.x;
    const int wave = tid >> 6, lane = tid & 63;
    const int l15  = lane & 15, quad = lane >> 4;

    f32x4 acc[4][4] = {};

    auto stage = [&](int kt, unsigned char* smbuf) {
        unsigned short* As = (unsigned short*)smbuf;
        float*          Bs = (float*)(smbuf + 32768);
        // A: 512 rows x 32 k bf16 = 2048 x 16B chunks; chunk c -> row c>>2
        #pragma unroll
        for (int ii = 0; ii < 4; ++ii) {
            const int c   = tid + ii * 512;
            const int row = c >> 2, cc = c & 3;
            const int ksw = cc ^ ((row >> 1) & 3);
            gld_lds16(xbf + (size_t)row * K_PAD + kt * 32 + ksw * 8,
                      (void*)(As + c * 8));
        }
        // B: 64 rows x 32 k f32 = 512 x 16B chunks; chunk c -> row c>>3
        {
            const int c   = tid;
            const int row = c >> 3, cc = c & 7;
            const int ksw = cc ^ (row & 7);
            int ko = kt * 32 + ksw * 4;
            if (ko > K_REAL - 4) ko = K_REAL - 4;   // kt=31 tail clamp
            gld_lds16(ent + (size_t)(n0 + row) * K_REAL + ko,
                      (void*)(Bs + c * 4));
        }
    };

    auto compute = [&](const unsigned char* smbuf) {
        const unsigned short* As = (const unsigned short*)smbuf;
        const float*          Bs = (const float*)(smbuf + 32768);
        short8 a[4], b[4];
        #pragma unroll
        for (int mi = 0; mi < 4; ++mi) {
            const int row = wave * 64 + mi * 16 + l15;
            a[mi] = *(const short8*)(As + row * 32 + (quad ^ ((row >> 1) & 3)) * 8);
        }
        #pragma unroll
        for (int ni = 0; ni < 4; ++ni) {
            const int row = ni * 16 + l15;
            const int sw  = row & 7;
            const float4 c0 = *(const float4*)(Bs + row * 32 + ((2 * quad)     ^ sw) * 4);
            const float4 c1 = *(const float4*)(Bs + row * 32 + ((2 * quad + 1) ^ sw) * 4);
            union { unsigned int u[4]; short8 s; } pk;
            pk.u[0] = pack_hi(c0.x, c0.y);
            pk.u[1] = pack_hi(c0.z, c0.w);
            pk.u[2] = pack_hi(c1.x, c1.y);
            pk.u[3] = pack_hi(c1.z, c1.w);
            b[ni] = pk.s;
        }
        #pragma unroll
        for (int mi = 0; mi < 4; ++mi)
            #pragma unroll
            for (int ni = 0; ni < 4; ++ni)
                acc[mi][ni] = __builtin_amdgcn_mfma_f32_16x16x32_bf16(
                    a[mi], b[ni], acc[mi][ni], 0, 0, 0);
    };

    // prologue
    stage(0, smx);
    __syncthreads();

    // 2-phase main loop: stage(t+1) -> compute(t) -> sync (drains stage t+1)
    for (int kt = 0; kt < 31; ++kt) {
        stage(kt + 1, smx + ((kt + 1) & 1) * 40960);
        compute(smx + (kt & 1) * 40960);
        __syncthreads();
    }
    compute(smx + 40960);                 // kt = 31 (buf 1), nothing to prefetch

    // ---- epilogue: LDS transpose (buf0 region), 256B-contiguous stores ----
    const int EPS = 68;                   // 64 + 4 pad
    float* ep = (float*)smx;              // 128*68*4 = 34816 B (buf0 only;
                                          // any wave still in compute(31)
                                          // touches buf1 -> disjoint)
    #pragma unroll
    for (int mi = 0; mi < 4; ++mi) {
        if (mi) __syncthreads();          // prior read phase done
        #pragma unroll
        for (int ni = 0; ni < 4; ++ni)
            #pragma unroll
            for (int r = 0; r < 4; ++r)
                ep[(wave * 16 + quad * 4 + r) * EPS + ni * 16 + l15] =
                    acc[mi][ni][r];
        __syncthreads();
        #pragma unroll
        for (int p = 0; p < 4; ++p) {
            const int idx  = p * 512 + tid;
            const int lrow = idx >> 4;              // 0..127
            const int c4   = idx & 15;
            const int grow = (lrow >> 4) * 64 + mi * 16 + (lrow & 15);
            if (grow < NB) {
                const float4 v = *(const float4*)(ep + lrow * EPS + c4 * 4);
                float4 o;
                o.x = 2.0f + 0.01f * v.x; o.y = 2.0f + 0.01f * v.y;
                o.z = 2.0f + 0.01f * v.z; o.w = 2.0f + 0.01f * v.w;
                *(float4*)(out + (size_t)grow * N_ENT + n0 + c4 * 4) = o;
            }
        }
    }
}

extern "C" void kernel_launch(void* const* d_in, const int* in_sizes, int n_in,
                              void* d_out, int out_size, void* d_ws, size_t ws_size,
                              hipStream_t stream) {
    const int*   queries = (const int*)d_in[0];
    const float* ent     = (const float*)d_in[1];
    const float* rot     = (const float*)d_in[2];
    const float* boo     = (const float*)d_in[3];
    float*       out     = (float*)d_out;
    unsigned short* xbf  = (unsigned short*)d_ws;   // [512][1024] bf16 = 1 MB

    lkg_prep<<<M_PAD, 256, 0, stream>>>(queries, ent, rot, boo, xbf, out);
    lkg_gemm5<<<dim3(625), 512, 0, stream>>>(xbf, ent, out);
}

// Round 2
// 292.826 us; speedup vs baseline: 1.2539x; 1.2539x over previous
//
#include <hip/hip_runtime.h>
#include <hip/hip_bf16.h>
#include <math.h>

#define N_ENT   40000
#define RANK    200
#define NB      500
#define K_REAL  1000   // RANK*5
#define K_PAD   1024
#define M_PAD   512
#define BN      160    // 40000/160 = 250 blocks exactly, <= 256 CUs, one round

typedef __attribute__((ext_vector_type(8))) short       short8;    // 8 bf16 MFMA A/B frag
typedef __attribute__((ext_vector_type(4))) float       f32x4;     // MFMA C/D frag

__device__ __forceinline__ unsigned short f2bf(float f) {
    union { float f; unsigned int u; } v; v.f = f;
    unsigned int u = v.u;
    return (unsigned short)((u + 0x7FFFu + ((u >> 16) & 1u)) >> 16);  // RNE
}

// truncating bf16x2 pack: low half from x, high half from y
__device__ __forceinline__ unsigned int pack_hi(float x, float y) {
    return (__float_as_uint(x) >> 16) | (__float_as_uint(y) & 0xFFFF0000u);
}

// async global->LDS 16B: HW writes wave-uniform LDS base + lane*16
__device__ __forceinline__ void gld_lds16(const void* g, void* l) {
    __builtin_amdgcn_global_load_lds(
        (const __attribute__((address_space(1))) unsigned int*)g,
        (__attribute__((address_space(3))) unsigned int*)l,
        16, 0, 0);
}

// ---------------------------------------------------------------------------
// gather + gelu/rotate/boost/negate -> x bf16 [512][1024] padded; reg_rel f32
// (unchanged from verified kernel)
// ---------------------------------------------------------------------------
__global__ __launch_bounds__(256) void lkg_prep(
    const int* __restrict__ queries,
    const float* __restrict__ ent,
    const float* __restrict__ rot,
    const float* __restrict__ boo,
    unsigned short* __restrict__ xws,
    float* __restrict__ out)
{
    const int b   = blockIdx.x;
    const int tid = threadIdx.x;
    unsigned short* xrow = xws + (size_t)b * K_PAD;

    if (b >= NB) {                       // zero pad rows 500..511
        ((uint2*)xrow)[tid] = make_uint2(0u, 0u);
        return;
    }
    if (tid >= RANK) {                   // zero K-pad cols 1000..1023
        int c = tid - RANK;
        if (c < K_PAD - K_REAL) xrow[K_REAL + c] = 0;
        return;
    }

    const int d  = tid;
    const int q0 = queries[b * 3 + 0];
    const int q1 = queries[b * 3 + 1];

    const float* L  = ent + (size_t)q0 * (RANK * 5) + d * 5;
    const float* R  = rot + (size_t)q1 * (RANK * 4) + d * 4;
    const float* Bo = boo + (size_t)q1 * (RANK * 4) + d * 4;

    const float t = L[0], r = L[1], i = L[2], j = L[3], k = L[4];
    const float r0 = R[0],  r1 = R[1],  r2 = R[2],  r3 = R[3];
    const float o0 = Bo[0], o1 = Bo[1], o2 = Bo[2], o3 = Bo[3];

    out[(size_t)NB * N_ENT + (size_t)b * RANK + d] =
        sqrtf(r0*r0 + r1*r1 + r2*r2 + r3*r3) +
        sqrtf(o0*o0 + o1*o1 + o2*o2 + o3*o3);

    const float is2 = 0.70710678118654752440f;
    const float rr = 0.5f * r0 * (1.0f + erff(r0 * is2));
    const float ri = 0.5f * r1 * (1.0f + erff(r1 * is2));
    const float rj = 0.5f * r2 * (1.0f + erff(r2 * is2));
    const float rk = 0.5f * r3 * (1.0f + erff(r3 * is2));

    const float s0 = r*rr - i*ri - j*rj - k*rk;
    const float s1 = r*ri + rr*i + j*rk - rj*k;
    const float s2 = r*rj + rr*j + k*ri - rk*i;
    const float s3 = r*rk + rr*k + i*rj - ri*j;

    const float b0 = 0.25f / (1.0f + expf(-o0));
    const float b1 = 0.25f / (1.0f + expf(-o1));
    const float b2 = 0.25f / (1.0f + expf(-o2));
    const float b3 = 0.25f / (1.0f + expf(-o3));

    const float bsq = b0*b0 + b1*b1 + b2*b2 + b3*b3;
    const float xt  = t * bsq + b0*s0 + b1*s1 + b2*s2 + b3*s3;

    const float m00 = sqrtf(1.0f + b0*b0), m11 = sqrtf(1.0f + b1*b1);
    const float m22 = sqrtf(1.0f + b2*b2), m33 = sqrtf(1.0f + b3*b3);
    const float m01 = sqrtf(b0*b1), m02 = sqrtf(b0*b2), m03 = sqrtf(b0*b3);
    const float m12 = sqrtf(b1*b2), m13 = sqrtf(b1*b3), m23 = sqrtf(b2*b3);

    const float xs0 = t*b0 + m00*s0 + m01*s1 + m02*s2 + m03*s3;
    const float xs1 = t*b1 + m01*s0 + m11*s1 + m12*s2 + m13*s3;
    const float xs2 = t*b2 + m02*s0 + m12*s1 + m22*s2 + m23*s3;
    const float xs3 = t*b3 + m03*s0 + m13*s1 + m23*s2 + m33*s3;

    unsigned short* w = xrow + d * 5;
    w[0] = f2bf(-xt);
    w[1] = f2bf(xs0);
    w[2] = f2bf(xs1);
    w[3] = f2bf(xs2);
    w[4] = f2bf(xs3);
}

// ---------------------------------------------------------------------------
// GEMM v6: traffic-minimal geometry. Tile = 512m x 160n, grid = 250 blocks
// (exact, one dispatch round, no tail), 512 threads = 8 waves, wave w owns
// m-rows [64w,64w+64) x all 160 n (acc[4][10]).
// Staged traffic: B (ent) exactly once = 160 MB; A (xbf) 250x1 MB = 250 MB;
// total 410 MB vs v5's 800 MB / v4's 961 MB. At the measured ~10-11 B/cyc/CU
// staging pace this predicts ~65 us + epilogue.
// 2-phase dbuf loop (stage(t+1) -> compute(t) -> sync), B staged before A
// (HBM latency > L2 latency for A, which is L2-resident everywhere).
// Swizzles identical to v4/v5 (on the GLOBAL address; LDS stays lane-linear
// as global_load_lds requires):
//   A: chunk cc stores k-chunk cc ^ ((row>>1)&3)
//   B: chunk cc stores k-chunk cc ^ (row&7)
// B tail kt=31: k>=1000 slots clamp source addr to k=996 -> finite garbage
// multiplied by A's zero-pad columns (xbf cols 1000..1023 are 0).
// LDS: 2 x (A 32KB + B 20KB) = 104 KB -> 1 block/CU; launch_bounds(512,2)
// caps VGPR at 256 (est ~220 incl acc 160).
// ---------------------------------------------------------------------------
#define BUFB 53248   // per-buffer bytes: A 32768 + B 20480

__global__ __launch_bounds__(512, 2) void lkg_gemm6(
    const unsigned short* __restrict__ xbf,
    const float* __restrict__ ent,
    float* __restrict__ out)
{
    __shared__ __align__(16) unsigned char smx[2 * BUFB];   // 104 KB

    const int n0   = blockIdx.x * BN;
    const int tid  = threadIdx.x;
    const int wave = tid >> 6, lane = tid & 63;
    const int l15  = lane & 15, quad = lane >> 4;

    f32x4 acc[4][10] = {};

    auto stage = [&](int kt, unsigned char* smbuf) {
        unsigned short* As = (unsigned short*)smbuf;
        float*          Bs = (float*)(smbuf + 32768);
        // B first (HBM latency): 160 rows x 32 k f32 = 1280 x 16B chunks
        #pragma unroll
        for (int ii = 0; ii < 3; ++ii) {
            const int c = tid + ii * 512;
            if (c < 1280) {                          // ii==2: waves 0..3 only
                const int row = c >> 3, cc = c & 7;
                const int ksw = cc ^ (row & 7);
                int ko = kt * 32 + ksw * 4;
                if (ko > K_REAL - 4) ko = K_REAL - 4;   // kt=31 tail clamp
                gld_lds16(ent + (size_t)(n0 + row) * K_REAL + ko,
                          (void*)(Bs + c * 4));
            }
        }
        // A: 512 rows x 32 k bf16 = 2048 x 16B chunks (L2-resident xbf)
        #pragma unroll
        for (int ii = 0; ii < 4; ++ii) {
            const int c   = tid + ii * 512;
            const int row = c >> 2, cc = c & 3;
            const int ksw = cc ^ ((row >> 1) & 3);
            gld_lds16(xbf + (size_t)row * K_PAD + kt * 32 + ksw * 8,
                      (void*)(As + c * 8));
        }
    };

    auto compute = [&](const unsigned char* smbuf) {
        const unsigned short* As = (const unsigned short*)smbuf;
        const float*          Bs = (const float*)(smbuf + 32768);
        short8 a[4];
        #pragma unroll
        for (int mi = 0; mi < 4; ++mi) {
            const int row = wave * 64 + mi * 16 + l15;
            a[mi] = *(const short8*)(As + row * 32 + (quad ^ ((row >> 1) & 3)) * 8);
        }
        #pragma unroll
        for (int ni = 0; ni < 10; ++ni) {
            const int row = ni * 16 + l15;
            const int sw  = row & 7;
            const float4 c0 = *(const float4*)(Bs + row * 32 + ((2 * quad)     ^ sw) * 4);
            const float4 c1 = *(const float4*)(Bs + row * 32 + ((2 * quad + 1) ^ sw) * 4);
            union { unsigned int u[4]; short8 s; } pk;
            pk.u[0] = pack_hi(c0.x, c0.y);
            pk.u[1] = pack_hi(c0.z, c0.w);
            pk.u[2] = pack_hi(c1.x, c1.y);
            pk.u[3] = pack_hi(c1.z, c1.w);
            #pragma unroll
            for (int mi = 0; mi < 4; ++mi)
                acc[mi][ni] = __builtin_amdgcn_mfma_f32_16x16x32_bf16(
                    a[mi], pk.s, acc[mi][ni], 0, 0, 0);
        }
    };

    // prologue
    stage(0, smx);
    __syncthreads();

    // 2-phase main loop: stage(t+1) -> compute(t) -> sync (drains stage t+1)
    for (int kt = 0; kt < 31; ++kt) {
        stage(kt + 1, smx + ((kt + 1) & 1) * BUFB);
        compute(smx + (kt & 1) * BUFB);
        __syncthreads();
    }
    compute(smx + BUFB);                  // kt = 31 (buf 1), nothing to prefetch

    // ---- epilogue: LDS transpose, 640B-contiguous store runs ----
    const int EPS = BN + 4;               // 164: +4 pad, <=2-way aliasing
    float* ep = (float*)smx;              // 128*164*4 = 83968 B (overlaps buf1
                                          // -> sync before every write phase)
    #pragma unroll
    for (int mi = 0; mi < 4; ++mi) {
        __syncthreads();                  // prior reads (incl. compute kt=31) done
        #pragma unroll
        for (int ni = 0; ni < 10; ++ni)
            #pragma unroll
            for (int r = 0; r < 4; ++r)
                ep[(wave * 16 + quad * 4 + r) * EPS + ni * 16 + l15] =
                    acc[mi][ni][r];
        __syncthreads();
        // 128 rows x 40 float4/row = 5120 stores; 10 per thread
        #pragma unroll
        for (int p = 0; p < 10; ++p) {
            const int idx = p * 512 + tid;
            const int lr  = idx / 40;               // magic-mul, epilogue only
            const int c4  = idx - lr * 40;
            const int grow = (lr >> 4) * 64 + mi * 16 + (lr & 15);
            if (grow < NB) {
                const float4 v = *(const float4*)(ep + lr * EPS + c4 * 4);
                float4 o;
                o.x = 2.0f + 0.01f * v.x; o.y = 2.0f + 0.01f * v.y;
                o.z = 2.0f + 0.01f * v.z; o.w = 2.0f + 0.01f * v.w;
                *(float4*)(out + (size_t)grow * N_ENT + n0 + c4 * 4) = o;
            }
        }
    }
}

extern "C" void kernel_launch(void* const* d_in, const int* in_sizes, int n_in,
                              void* d_out, int out_size, void* d_ws, size_t ws_size,
                              hipStream_t stream) {
    const int*   queries = (const int*)d_in[0];
    const float* ent     = (const float*)d_in[1];
    const float* rot     = (const float*)d_in[2];
    const float* boo     = (const float*)d_in[3];
    float*       out     = (float*)d_out;
    unsigned short* xbf  = (unsigned short*)d_ws;   // [512][1024] bf16 = 1 MB

    lkg_prep<<<M_PAD, 256, 0, stream>>>(queries, ent, rot, boo, xbf, out);
    lkg_gemm6<<<dim3(N_ENT / BN), 512, 0, stream>>>(xbf, ent, out);
}